// Round 1
// baseline (2963.977 us; speedup 1.0000x reference)
//
#include <hip/hip_runtime.h>
#include <hip/hip_bf16.h>

#define H 128

typedef __bf16 bf16_t;
typedef __attribute__((ext_vector_type(8))) __bf16 bf16x8;
typedef __attribute__((ext_vector_type(4))) float f32x4;

static_assert(sizeof(bf16x8) == 16, "bf16x8 must be 16 bytes");

// Load an A-fragment for mfma_f32_16x16x32_bf16:
// lane supplies A[row][koff .. koff+7] as 8 bf16 (koff = 32*t + (lane>>4)*8)
__device__ inline bf16x8 load_a_frag(const float* __restrict__ A, int row, int koff) {
    const float4* p = (const float4*)(A + (size_t)row * H + koff);
    float4 v0 = p[0], v1 = p[1];
    bf16x8 r;
    r[0] = (bf16_t)v0.x; r[1] = (bf16_t)v0.y; r[2] = (bf16_t)v0.z; r[3] = (bf16_t)v0.w;
    r[4] = (bf16_t)v1.x; r[5] = (bf16_t)v1.y; r[6] = (bf16_t)v1.z; r[7] = (bf16_t)v1.w;
    return r;
}

// ---------------- weight prep: f32 -> bf16, [out_col][k] layout ----------------
__global__ void prep_weights(const float* __restrict__ Wf,  const float* __restrict__ Wih,
                             const float* __restrict__ Whh, const float* __restrict__ Wl1,
                             bf16_t* __restrict__ wfT, bf16_t* __restrict__ wih,
                             bf16_t* __restrict__ whh, bf16_t* __restrict__ wl1T) {
    int i = blockIdx.x * blockDim.x + threadIdx.x;
    if (i < 128 * 128) {
        int c = i >> 7, k = i & 127;
        wfT[i]  = (bf16_t)Wf[k * 128 + c];   // W_first: [k][c] -> [c][k]
        wl1T[i] = (bf16_t)Wl1[k * 128 + c];  // W_lin1 same
    }
    if (i < 384 * 128) {
        wih[i] = (bf16_t)Wih[i];             // torch [out][in] already [c][k]
        whh[i] = (bf16_t)Whh[i];
    }
}

// ---------------- out[n][c] = sum_k A[n][k]*Bt[c][k] + bias[c] ----------------
// Bt: bf16 [128][128] (row = output col, contiguous k). 32 rows per wave.
__global__ __launch_bounds__(256) void lin128_kernel(
    const float* __restrict__ A, const bf16_t* __restrict__ Bt,
    const float* __restrict__ bias, float* __restrict__ out, int n) {
    int wid = threadIdx.x >> 6, lane = threadIdx.x & 63;
    int r0 = (blockIdx.x * 4 + wid) * 32;
    if (r0 >= n) return;
    int lrow = lane & 15, lk8 = (lane >> 4) * 8;

    bf16x8 a[2][4];
    for (int rt = 0; rt < 2; ++rt) {
        int row = r0 + rt * 16 + lrow;
        if (row >= n) row = n - 1;
        for (int t = 0; t < 4; ++t) a[rt][t] = load_a_frag(A, row, t * 32 + lk8);
    }
    for (int ct = 0; ct < 8; ++ct) {
        int c0 = ct * 16;
        f32x4 acc0 = {0.f, 0.f, 0.f, 0.f}, acc1 = {0.f, 0.f, 0.f, 0.f};
        const bf16_t* bp = Bt + (size_t)(c0 + lrow) * H + lk8;
        for (int t = 0; t < 4; ++t) {
            bf16x8 b = *(const bf16x8*)(bp + t * 32);
            acc0 = __builtin_amdgcn_mfma_f32_16x16x32_bf16(a[0][t], b, acc0, 0, 0, 0);
            acc1 = __builtin_amdgcn_mfma_f32_16x16x32_bf16(a[1][t], b, acc1, 0, 0, 0);
        }
        int col = c0 + lrow;
        float bv = bias[col];
        for (int r = 0; r < 4; ++r) {
            int row0 = r0 + (lane >> 4) * 4 + r;
            if (row0 < n) out[(size_t)row0 * H + col] = acc0[r] + bv;
            int row1 = row0 + 16;
            if (row1 < n) out[(size_t)row1 * H + col] = acc1[r] + bv;
        }
    }
}

// ---------------- fused GRU cell ----------------
// gi = inp @ Wih^T + bih ; gh = hid @ Whh^T + bhh ; gates in-register
__global__ __launch_bounds__(256) void gru_kernel(
    const float* __restrict__ inp, const float* __restrict__ hid,
    const bf16_t* __restrict__ Wih, const bf16_t* __restrict__ Whh,
    const float* __restrict__ bih, const float* __restrict__ bhh,
    float* __restrict__ out, int n) {
    int wid = threadIdx.x >> 6, lane = threadIdx.x & 63;
    int r0 = (blockIdx.x * 4 + wid) * 32;
    if (r0 >= n) return;
    int lrow = lane & 15, lk8 = (lane >> 4) * 8;

    bf16x8 ai[2][4], ah[2][4];
    for (int rt = 0; rt < 2; ++rt) {
        int row = r0 + rt * 16 + lrow;
        if (row >= n) row = n - 1;
        for (int t = 0; t < 4; ++t) {
            ai[rt][t] = load_a_frag(inp, row, t * 32 + lk8);
            ah[rt][t] = load_a_frag(hid, row, t * 32 + lk8);
        }
    }
    for (int ct = 0; ct < 8; ++ct) {
        int c0 = ct * 16;
        int col = c0 + lrow;
        f32x4 air[2], aiz[2], ain[2], ahr[2], ahz[2], ahn[2];
        for (int rt = 0; rt < 2; ++rt) {
            air[rt] = (f32x4){0.f,0.f,0.f,0.f}; aiz[rt] = (f32x4){0.f,0.f,0.f,0.f};
            ain[rt] = (f32x4){0.f,0.f,0.f,0.f}; ahr[rt] = (f32x4){0.f,0.f,0.f,0.f};
            ahz[rt] = (f32x4){0.f,0.f,0.f,0.f}; ahn[rt] = (f32x4){0.f,0.f,0.f,0.f};
        }
        const bf16_t* pir = Wih + (size_t)(col)       * H + lk8;
        const bf16_t* piz = Wih + (size_t)(128 + col) * H + lk8;
        const bf16_t* pin = Wih + (size_t)(256 + col) * H + lk8;
        const bf16_t* phr = Whh + (size_t)(col)       * H + lk8;
        const bf16_t* phz = Whh + (size_t)(128 + col) * H + lk8;
        const bf16_t* phn = Whh + (size_t)(256 + col) * H + lk8;
        for (int t = 0; t < 4; ++t) {
            bf16x8 bir = *(const bf16x8*)(pir + t * 32);
            bf16x8 biz = *(const bf16x8*)(piz + t * 32);
            bf16x8 bin = *(const bf16x8*)(pin + t * 32);
            bf16x8 bhr = *(const bf16x8*)(phr + t * 32);
            bf16x8 bhz = *(const bf16x8*)(phz + t * 32);
            bf16x8 bhn = *(const bf16x8*)(phn + t * 32);
            for (int rt = 0; rt < 2; ++rt) {
                air[rt] = __builtin_amdgcn_mfma_f32_16x16x32_bf16(ai[rt][t], bir, air[rt], 0, 0, 0);
                aiz[rt] = __builtin_amdgcn_mfma_f32_16x16x32_bf16(ai[rt][t], biz, aiz[rt], 0, 0, 0);
                ain[rt] = __builtin_amdgcn_mfma_f32_16x16x32_bf16(ai[rt][t], bin, ain[rt], 0, 0, 0);
                ahr[rt] = __builtin_amdgcn_mfma_f32_16x16x32_bf16(ah[rt][t], bhr, ahr[rt], 0, 0, 0);
                ahz[rt] = __builtin_amdgcn_mfma_f32_16x16x32_bf16(ah[rt][t], bhz, ahz[rt], 0, 0, 0);
                ahn[rt] = __builtin_amdgcn_mfma_f32_16x16x32_bf16(ah[rt][t], bhn, ahn[rt], 0, 0, 0);
            }
        }
        float b_ir = bih[col], b_iz = bih[128 + col], b_in = bih[256 + col];
        float b_hr = bhh[col], b_hz = bhh[128 + col], b_hn = bhh[256 + col];
        for (int rt = 0; rt < 2; ++rt) {
            for (int r = 0; r < 4; ++r) {
                int row = r0 + rt * 16 + (lane >> 4) * 4 + r;
                float irv = air[rt][r] + b_ir, hrv = ahr[rt][r] + b_hr;
                float izv = aiz[rt][r] + b_iz, hzv = ahz[rt][r] + b_hz;
                float inv = ain[rt][r] + b_in, hnv = ahn[rt][r] + b_hn;
                float rg = 1.f / (1.f + __expf(-(irv + hrv)));
                float zg = 1.f / (1.f + __expf(-(izv + hzv)));
                float xx = inv + rg * hnv;
                float ng = 2.f / (1.f + __expf(-2.f * xx)) - 1.f;   // tanh
                if (row < n) {
                    float hv = hid[(size_t)row * H + col];
                    out[(size_t)row * H + col] = (1.f - zg) * ng + zg * hv;
                }
            }
        }
    }
}

// ---------------- gated conv: agg[dst] += x[src] * w ----------------
__global__ __launch_bounds__(256) void conv_kernel(
    const float* __restrict__ x, const int* __restrict__ ei,
    const float* __restrict__ ew, float* __restrict__ agg, int nE) {
    int lane = threadIdx.x & 63;
    int wid = (blockIdx.x * blockDim.x + threadIdx.x) >> 6;
    int nw = (gridDim.x * blockDim.x) >> 6;
    for (int e = wid; e < nE; e += nw) {
        int src = __builtin_amdgcn_readfirstlane(ei[e]);
        int dst = __builtin_amdgcn_readfirstlane(ei[nE + e]);
        float w = ew[e];
        float2 v = *(const float2*)(x + (size_t)src * H + lane * 2);
        float* ap = agg + (size_t)dst * H + lane * 2;
        unsafeAtomicAdd(ap, v.x * w);
        unsafeAtomicAdd(ap + 1, v.y * w);
    }
}

// ---------------- head: logits = x @ W_out + b_out ; log_softmax ----------------
__global__ __launch_bounds__(256) void head_kernel(
    const float* __restrict__ x, const float* __restrict__ Wout,
    const float* __restrict__ bout, float* __restrict__ out, int n) {
    int lane = threadIdx.x & 63;
    int node = (blockIdx.x * blockDim.x + threadIdx.x) >> 6;
    if (node >= n) return;
    float2 v = *(const float2*)(x + (size_t)node * H + lane * 2);
    float4 w = *(const float4*)(Wout + lane * 4);  // rows 2l,2l+1 x cols 0,1
    float s0 = v.x * w.x + v.y * w.z;
    float s1 = v.x * w.y + v.y * w.w;
    for (int off = 32; off; off >>= 1) {
        s0 += __shfl_down(s0, off);
        s1 += __shfl_down(s1, off);
    }
    if (lane == 0) {
        float l0 = s0 + bout[0], l1 = s1 + bout[1];
        float m = fmaxf(l0, l1);
        float lse = m + __logf(__expf(l0 - m) + __expf(l1 - m));
        out[(size_t)node * 2]     = l0 - lse;
        out[(size_t)node * 2 + 1] = l1 - lse;
    }
}

extern "C" void kernel_launch(void* const* d_in, const int* in_sizes, int n_in,
                              void* d_out, int out_size, void* d_ws, size_t ws_size,
                              hipStream_t stream) {
    const float* x   = (const float*)d_in[0];
    const int*   ei  = (const int*)d_in[1];
    const float* ew  = (const float*)d_in[2];
    const float* Wf  = (const float*)d_in[3];
    const float* bf  = (const float*)d_in[4];
    const float* Wih = (const float*)d_in[5];
    const float* bih = (const float*)d_in[6];
    const float* Whh = (const float*)d_in[7];
    const float* bhh = (const float*)d_in[8];
    const float* Wl1 = (const float*)d_in[9];
    const float* bl1 = (const float*)d_in[10];
    const float* Wo  = (const float*)d_in[11];
    const float* bo  = (const float*)d_in[12];

    int n  = in_sizes[0] / H;     // 100000
    int nE = in_sizes[2];         // 1600000 (edge_weight length)

    float* hbuf = (float*)d_ws;                    // [n][H]  first_lin output (GRU hidden)
    float* b1   = hbuf + (size_t)n * H;            // [n][H]  agg1 / g1 / l1
    float* b2   = b1 + (size_t)n * H;              // [n][H]  agg2 / g2
    bf16_t* wfT  = (bf16_t*)(b2 + (size_t)n * H);
    bf16_t* wih  = wfT + 128 * 128;
    bf16_t* whh  = wih + 384 * 128;
    bf16_t* wl1T = whh + 384 * 128;

    int gemmGrid = (n + 127) / 128;

    prep_weights<<<192, 256, 0, stream>>>(Wf, Wih, Whh, Wl1, wfT, wih, whh, wl1T);
    lin128_kernel<<<gemmGrid, 256, 0, stream>>>(x, wfT, bf, hbuf, n);

    hipMemsetAsync(b1, 0, (size_t)n * H * sizeof(float), stream);
    conv_kernel<<<4096, 256, 0, stream>>>(hbuf, ei, ew, b1, nE);
    gru_kernel<<<gemmGrid, 256, 0, stream>>>(b1, hbuf, wih, whh, bih, bhh, b1, n);
    lin128_kernel<<<gemmGrid, 256, 0, stream>>>(b1, wl1T, bl1, b1, n);

    hipMemsetAsync(b2, 0, (size_t)n * H * sizeof(float), stream);
    conv_kernel<<<4096, 256, 0, stream>>>(b1, ei, ew, b2, nE);
    gru_kernel<<<gemmGrid, 256, 0, stream>>>(b2, hbuf, wih, whh, bih, bhh, b2, n);

    head_kernel<<<(n + 3) / 4, 256, 0, stream>>>(b2, Wo, bo, (float*)d_out, n);
}

// Round 2
// 881.237 us; speedup vs baseline: 3.3634x; 3.3634x over previous
//
#include <hip/hip_runtime.h>
#include <hip/hip_bf16.h>

#define H 128
#define SCAN_T 256
#define SCAN_I 8
#define SCAN_CHUNK (SCAN_T * SCAN_I)   // 2048 elems per scan block

typedef __bf16 bf16_t;
typedef __attribute__((ext_vector_type(8))) __bf16 bf16x8;
typedef __attribute__((ext_vector_type(4))) float f32x4;

static_assert(sizeof(bf16x8) == 16, "bf16x8 must be 16 bytes");

// Load an A-fragment for mfma_f32_16x16x32_bf16:
// lane supplies A[row][koff .. koff+7] as 8 bf16 (koff = 32*t + (lane>>4)*8)
__device__ inline bf16x8 load_a_frag(const float* __restrict__ A, int row, int koff) {
    const float4* p = (const float4*)(A + (size_t)row * H + koff);
    float4 v0 = p[0], v1 = p[1];
    bf16x8 r;
    r[0] = (bf16_t)v0.x; r[1] = (bf16_t)v0.y; r[2] = (bf16_t)v0.z; r[3] = (bf16_t)v0.w;
    r[4] = (bf16_t)v1.x; r[5] = (bf16_t)v1.y; r[6] = (bf16_t)v1.z; r[7] = (bf16_t)v1.w;
    return r;
}

// ---------------- weight prep: f32 -> bf16, [out_col][k] layout ----------------
__global__ void prep_weights(const float* __restrict__ Wf,  const float* __restrict__ Wih,
                             const float* __restrict__ Whh, const float* __restrict__ Wl1,
                             bf16_t* __restrict__ wfT, bf16_t* __restrict__ wih,
                             bf16_t* __restrict__ whh, bf16_t* __restrict__ wl1T) {
    int i = blockIdx.x * blockDim.x + threadIdx.x;
    if (i < 128 * 128) {
        int c = i >> 7, k = i & 127;
        wfT[i]  = (bf16_t)Wf[k * 128 + c];   // W_first: [k][c] -> [c][k]
        wl1T[i] = (bf16_t)Wl1[k * 128 + c];  // W_lin1 same
    }
    if (i < 384 * 128) {
        wih[i] = (bf16_t)Wih[i];             // torch [out][in] already [c][k]
        whh[i] = (bf16_t)Whh[i];
    }
}

// ---------------- CSR build ----------------
__global__ void hist_kernel(const int* __restrict__ ei, int* __restrict__ deg, int nE) {
    int e = blockIdx.x * blockDim.x + threadIdx.x;
    if (e < nE) atomicAdd(&deg[ei[nE + e]], 1);
}

// block-level exclusive scan (2048 elems/block), block totals -> bsum
__global__ __launch_bounds__(SCAN_T) void scan1_kernel(
    const int* __restrict__ deg, int* __restrict__ rowptr, int* __restrict__ bsum, int n) {
    __shared__ int s[SCAN_T];
    int base = blockIdx.x * SCAN_CHUNK + threadIdx.x * SCAN_I;
    int v[SCAN_I];
    int sum = 0;
    for (int j = 0; j < SCAN_I; ++j) {
        int idx = base + j;
        v[j] = (idx < n) ? deg[idx] : 0;
        sum += v[j];
    }
    s[threadIdx.x] = sum;
    __syncthreads();
    for (int off = 1; off < SCAN_T; off <<= 1) {
        int t = (threadIdx.x >= off) ? s[threadIdx.x - off] : 0;
        __syncthreads();
        s[threadIdx.x] += t;
        __syncthreads();
    }
    int run = s[threadIdx.x] - sum;      // exclusive prefix across threads
    for (int j = 0; j < SCAN_I; ++j) {
        int idx = base + j;
        if (idx < n) rowptr[idx] = run;
        run += v[j];
    }
    if (threadIdx.x == SCAN_T - 1) bsum[blockIdx.x] = s[SCAN_T - 1];
}

// single-block exclusive scan of block sums (nb <= 256)
__global__ __launch_bounds__(SCAN_T) void scan2_kernel(int* __restrict__ bsum, int nb) {
    __shared__ int s[SCAN_T];
    int v = (threadIdx.x < nb) ? bsum[threadIdx.x] : 0;
    s[threadIdx.x] = v;
    __syncthreads();
    for (int off = 1; off < SCAN_T; off <<= 1) {
        int t = (threadIdx.x >= off) ? s[threadIdx.x - off] : 0;
        __syncthreads();
        s[threadIdx.x] += t;
        __syncthreads();
    }
    if (threadIdx.x < nb) bsum[threadIdx.x] = s[threadIdx.x] - v;  // exclusive
}

__global__ void scan3_kernel(int* __restrict__ rowptr, int* __restrict__ cursor,
                             const int* __restrict__ bsum, int n, int nE) {
    int idx = blockIdx.x * blockDim.x + threadIdx.x;
    if (idx < n) {
        int val = rowptr[idx] + bsum[idx / SCAN_CHUNK];
        rowptr[idx] = val;
        cursor[idx] = val;
    }
    if (idx == 0) rowptr[n] = nE;
}

__global__ void scatter_kernel(const int* __restrict__ ei, const float* __restrict__ ew,
                               int* __restrict__ cursor, int2* __restrict__ srcw, int nE) {
    int e = blockIdx.x * blockDim.x + threadIdx.x;
    if (e < nE) {
        int src = ei[e], dst = ei[nE + e];
        float w = ew[e];
        int pos = atomicAdd(&cursor[dst], 1);
        srcw[pos] = make_int2(src, __float_as_int(w));
    }
}

// ---------------- gated conv via CSR: one wave per dst node, no atomics ----------------
__global__ __launch_bounds__(256) void conv_csr_kernel(
    const float* __restrict__ x, const int* __restrict__ rowptr,
    const int2* __restrict__ srcw, float* __restrict__ agg, int n) {
    int lane = threadIdx.x & 63;
    int d = (blockIdx.x * blockDim.x + threadIdx.x) >> 6;
    if (d >= n) return;
    int beg = rowptr[d], end = rowptr[d + 1];
    float ax = 0.f, ay = 0.f;
    for (int e = beg; e < end; ++e) {
        int2 sw = srcw[e];
        int src = __builtin_amdgcn_readfirstlane(sw.x);
        float w = __int_as_float(__builtin_amdgcn_readfirstlane(sw.y));
        float2 v = *(const float2*)(x + (size_t)src * H + lane * 2);
        ax += v.x * w;
        ay += v.y * w;
    }
    float2 r = make_float2(ax, ay);
    *(float2*)(agg + (size_t)d * H + lane * 2) = r;
}

// ---------------- out[n][c] = sum_k A[n][k]*Bt[c][k] + bias[c] ----------------
__global__ __launch_bounds__(256) void lin128_kernel(
    const float* __restrict__ A, const bf16_t* __restrict__ Bt,
    const float* __restrict__ bias, float* __restrict__ out, int n) {
    int wid = threadIdx.x >> 6, lane = threadIdx.x & 63;
    int r0 = (blockIdx.x * 4 + wid) * 32;
    if (r0 >= n) return;
    int lrow = lane & 15, lk8 = (lane >> 4) * 8;

    bf16x8 a[2][4];
    for (int rt = 0; rt < 2; ++rt) {
        int row = r0 + rt * 16 + lrow;
        if (row >= n) row = n - 1;
        for (int t = 0; t < 4; ++t) a[rt][t] = load_a_frag(A, row, t * 32 + lk8);
    }
    for (int ct = 0; ct < 8; ++ct) {
        int c0 = ct * 16;
        f32x4 acc0 = {0.f, 0.f, 0.f, 0.f}, acc1 = {0.f, 0.f, 0.f, 0.f};
        const bf16_t* bp = Bt + (size_t)(c0 + lrow) * H + lk8;
        for (int t = 0; t < 4; ++t) {
            bf16x8 b = *(const bf16x8*)(bp + t * 32);
            acc0 = __builtin_amdgcn_mfma_f32_16x16x32_bf16(a[0][t], b, acc0, 0, 0, 0);
            acc1 = __builtin_amdgcn_mfma_f32_16x16x32_bf16(a[1][t], b, acc1, 0, 0, 0);
        }
        int col = c0 + lrow;
        float bv = bias[col];
        for (int r = 0; r < 4; ++r) {
            int row0 = r0 + (lane >> 4) * 4 + r;
            if (row0 < n) out[(size_t)row0 * H + col] = acc0[r] + bv;
            int row1 = row0 + 16;
            if (row1 < n) out[(size_t)row1 * H + col] = acc1[r] + bv;
        }
    }
}

// ---------------- fused GRU cell ----------------
__global__ __launch_bounds__(256) void gru_kernel(
    const float* __restrict__ inp, const float* __restrict__ hid,
    const bf16_t* __restrict__ Wih, const bf16_t* __restrict__ Whh,
    const float* __restrict__ bih, const float* __restrict__ bhh,
    float* __restrict__ out, int n) {
    int wid = threadIdx.x >> 6, lane = threadIdx.x & 63;
    int r0 = (blockIdx.x * 4 + wid) * 32;
    if (r0 >= n) return;
    int lrow = lane & 15, lk8 = (lane >> 4) * 8;

    bf16x8 ai[2][4], ah[2][4];
    for (int rt = 0; rt < 2; ++rt) {
        int row = r0 + rt * 16 + lrow;
        if (row >= n) row = n - 1;
        for (int t = 0; t < 4; ++t) {
            ai[rt][t] = load_a_frag(inp, row, t * 32 + lk8);
            ah[rt][t] = load_a_frag(hid, row, t * 32 + lk8);
        }
    }
    for (int ct = 0; ct < 8; ++ct) {
        int c0 = ct * 16;
        int col = c0 + lrow;
        f32x4 air[2], aiz[2], ain[2], ahr[2], ahz[2], ahn[2];
        for (int rt = 0; rt < 2; ++rt) {
            air[rt] = (f32x4){0.f,0.f,0.f,0.f}; aiz[rt] = (f32x4){0.f,0.f,0.f,0.f};
            ain[rt] = (f32x4){0.f,0.f,0.f,0.f}; ahr[rt] = (f32x4){0.f,0.f,0.f,0.f};
            ahz[rt] = (f32x4){0.f,0.f,0.f,0.f}; ahn[rt] = (f32x4){0.f,0.f,0.f,0.f};
        }
        const bf16_t* pir = Wih + (size_t)(col)       * H + lk8;
        const bf16_t* piz = Wih + (size_t)(128 + col) * H + lk8;
        const bf16_t* pin = Wih + (size_t)(256 + col) * H + lk8;
        const bf16_t* phr = Whh + (size_t)(col)       * H + lk8;
        const bf16_t* phz = Whh + (size_t)(128 + col) * H + lk8;
        const bf16_t* phn = Whh + (size_t)(256 + col) * H + lk8;
        for (int t = 0; t < 4; ++t) {
            bf16x8 bir = *(const bf16x8*)(pir + t * 32);
            bf16x8 biz = *(const bf16x8*)(piz + t * 32);
            bf16x8 bin = *(const bf16x8*)(pin + t * 32);
            bf16x8 bhr = *(const bf16x8*)(phr + t * 32);
            bf16x8 bhz = *(const bf16x8*)(phz + t * 32);
            bf16x8 bhn = *(const bf16x8*)(phn + t * 32);
            for (int rt = 0; rt < 2; ++rt) {
                air[rt] = __builtin_amdgcn_mfma_f32_16x16x32_bf16(ai[rt][t], bir, air[rt], 0, 0, 0);
                aiz[rt] = __builtin_amdgcn_mfma_f32_16x16x32_bf16(ai[rt][t], biz, aiz[rt], 0, 0, 0);
                ain[rt] = __builtin_amdgcn_mfma_f32_16x16x32_bf16(ai[rt][t], bin, ain[rt], 0, 0, 0);
                ahr[rt] = __builtin_amdgcn_mfma_f32_16x16x32_bf16(ah[rt][t], bhr, ahr[rt], 0, 0, 0);
                ahz[rt] = __builtin_amdgcn_mfma_f32_16x16x32_bf16(ah[rt][t], bhz, ahz[rt], 0, 0, 0);
                ahn[rt] = __builtin_amdgcn_mfma_f32_16x16x32_bf16(ah[rt][t], bhn, ahn[rt], 0, 0, 0);
            }
        }
        float b_ir = bih[col], b_iz = bih[128 + col], b_in = bih[256 + col];
        float b_hr = bhh[col], b_hz = bhh[128 + col], b_hn = bhh[256 + col];
        for (int rt = 0; rt < 2; ++rt) {
            for (int r = 0; r < 4; ++r) {
                int row = r0 + rt * 16 + (lane >> 4) * 4 + r;
                float irv = air[rt][r] + b_ir, hrv = ahr[rt][r] + b_hr;
                float izv = aiz[rt][r] + b_iz, hzv = ahz[rt][r] + b_hz;
                float inv = ain[rt][r] + b_in, hnv = ahn[rt][r] + b_hn;
                float rg = 1.f / (1.f + __expf(-(irv + hrv)));
                float zg = 1.f / (1.f + __expf(-(izv + hzv)));
                float xx = inv + rg * hnv;
                float ng = 2.f / (1.f + __expf(-2.f * xx)) - 1.f;   // tanh
                if (row < n) {
                    float hv = hid[(size_t)row * H + col];
                    out[(size_t)row * H + col] = (1.f - zg) * ng + zg * hv;
                }
            }
        }
    }
}

// ---------------- head: logits = x @ W_out + b_out ; log_softmax ----------------
__global__ __launch_bounds__(256) void head_kernel(
    const float* __restrict__ x, const float* __restrict__ Wout,
    const float* __restrict__ bout, float* __restrict__ out, int n) {
    int lane = threadIdx.x & 63;
    int node = (blockIdx.x * blockDim.x + threadIdx.x) >> 6;
    if (node >= n) return;
    float2 v = *(const float2*)(x + (size_t)node * H + lane * 2);
    float4 w = *(const float4*)(Wout + lane * 4);  // rows 2l,2l+1 x cols 0,1
    float s0 = v.x * w.x + v.y * w.z;
    float s1 = v.x * w.y + v.y * w.w;
    for (int off = 32; off; off >>= 1) {
        s0 += __shfl_down(s0, off);
        s1 += __shfl_down(s1, off);
    }
    if (lane == 0) {
        float l0 = s0 + bout[0], l1 = s1 + bout[1];
        float m = fmaxf(l0, l1);
        float lse = m + __logf(__expf(l0 - m) + __expf(l1 - m));
        out[(size_t)node * 2]     = l0 - lse;
        out[(size_t)node * 2 + 1] = l1 - lse;
    }
}

extern "C" void kernel_launch(void* const* d_in, const int* in_sizes, int n_in,
                              void* d_out, int out_size, void* d_ws, size_t ws_size,
                              hipStream_t stream) {
    const float* x   = (const float*)d_in[0];
    const int*   ei  = (const int*)d_in[1];
    const float* ew  = (const float*)d_in[2];
    const float* Wf  = (const float*)d_in[3];
    const float* bf  = (const float*)d_in[4];
    const float* Wih = (const float*)d_in[5];
    const float* bih = (const float*)d_in[6];
    const float* Whh = (const float*)d_in[7];
    const float* bhh = (const float*)d_in[8];
    const float* Wl1 = (const float*)d_in[9];
    const float* bl1 = (const float*)d_in[10];
    const float* Wo  = (const float*)d_in[11];
    const float* bo  = (const float*)d_in[12];

    int n  = in_sizes[0] / H;     // 100000
    int nE = in_sizes[2];         // 1600000 (edge_weight length)

    float* hbuf = (float*)d_ws;                    // [n][H]  first_lin output (GRU hidden)
    float* b1   = hbuf + (size_t)n * H;            // [n][H]  agg1 / g1 / l1
    float* b2   = b1 + (size_t)n * H;              // [n][H]  agg2 / g2
    bf16_t* wfT  = (bf16_t*)(b2 + (size_t)n * H);
    bf16_t* wih  = wfT + 128 * 128;
    bf16_t* whh  = wih + 384 * 128;
    bf16_t* wl1T = whh + 384 * 128;
    int* deg    = (int*)(wl1T + 128 * 128);        // [n]
    int* rowptr = deg + n;                         // [n+1]
    int* cursor = rowptr + (n + 1);                // [n]
    int2* srcw  = (int2*)((char*)(cursor + n) + ((size_t)(-(intptr_t)(cursor + n)) & 7)); // [nE], 8B aligned

    int gemmGrid = (n + 127) / 128;
    int nScanBlocks = (n + SCAN_CHUNK - 1) / SCAN_CHUNK;

    // ---- one-time per launch: weights + CSR build ----
    prep_weights<<<192, 256, 0, stream>>>(Wf, Wih, Whh, Wl1, wfT, wih, whh, wl1T);
    hipMemsetAsync(deg, 0, (size_t)n * sizeof(int), stream);
    hist_kernel<<<(nE + 255) / 256, 256, 0, stream>>>(ei, deg, nE);
    scan1_kernel<<<nScanBlocks, SCAN_T, 0, stream>>>(deg, rowptr, cursor /*reuse as bsum? no*/, n);
    // NOTE: bsum stored in `deg` head is unsafe (deg still needed? no - deg unused after scan1).
    // We used `cursor` as bsum above; scan2 operates on it, scan3 writes real cursor afterwards.
    scan2_kernel<<<1, SCAN_T, 0, stream>>>(cursor, nScanBlocks);
    scan3_kernel<<<(n + 255) / 256, 256, 0, stream>>>(rowptr, deg /*becomes cursor*/, cursor, n, nE);
    scatter_kernel<<<(nE + 255) / 256, 256, 0, stream>>>(ei, ew, deg, srcw, nE);

    // ---- pipeline ----
    lin128_kernel<<<gemmGrid, 256, 0, stream>>>(x, wfT, bf, hbuf, n);
    conv_csr_kernel<<<(n + 3) / 4, 256, 0, stream>>>(hbuf, rowptr, srcw, b1, n);
    gru_kernel<<<gemmGrid, 256, 0, stream>>>(b1, hbuf, wih, whh, bih, bhh, b1, n);
    lin128_kernel<<<gemmGrid, 256, 0, stream>>>(b1, wl1T, bl1, b1, n);
    conv_csr_kernel<<<(n + 3) / 4, 256, 0, stream>>>(b1, rowptr, srcw, b2, n);
    gru_kernel<<<gemmGrid, 256, 0, stream>>>(b2, hbuf, wih, whh, bih, bhh, b2, n);
    head_kernel<<<(n + 3) / 4, 256, 0, stream>>>(b2, Wo, bo, (float*)d_out, n);
}

// Round 3
// 792.041 us; speedup vs baseline: 3.7422x; 1.1126x over previous
//
#include <hip/hip_runtime.h>
#include <hip/hip_bf16.h>

#define H 128
#define SCAN_T 256
#define SCAN_I 8
#define SCAN_CHUNK (SCAN_T * SCAN_I)   // 2048 elems per scan block

typedef __bf16 bf16_t;
typedef __attribute__((ext_vector_type(2))) __bf16 bf16x2;
typedef __attribute__((ext_vector_type(8))) __bf16 bf16x8;
typedef __attribute__((ext_vector_type(4))) float f32x4;

static_assert(sizeof(bf16x8) == 16, "bf16x8 must be 16 bytes");

// f32 source -> A-fragment (8 bf16) for mfma_f32_16x16x32_bf16
__device__ inline bf16x8 load_a_frag_f32(const float* __restrict__ A, int row, int koff) {
    const float4* p = (const float4*)(A + (size_t)row * H + koff);
    float4 v0 = p[0], v1 = p[1];
    bf16x8 r;
    r[0] = (bf16_t)v0.x; r[1] = (bf16_t)v0.y; r[2] = (bf16_t)v0.z; r[3] = (bf16_t)v0.w;
    r[4] = (bf16_t)v1.x; r[5] = (bf16_t)v1.y; r[6] = (bf16_t)v1.z; r[7] = (bf16_t)v1.w;
    return r;
}

// ---------------- weight prep ----------------
__global__ void prep_weights(const float* __restrict__ Wf,  const float* __restrict__ Wih,
                             const float* __restrict__ Whh, const float* __restrict__ Wl1,
                             bf16_t* __restrict__ wfT, bf16_t* __restrict__ wih,
                             bf16_t* __restrict__ whh, bf16_t* __restrict__ wl1T) {
    int i = blockIdx.x * blockDim.x + threadIdx.x;
    if (i < 128 * 128) {
        int c = i >> 7, k = i & 127;
        wfT[i]  = (bf16_t)Wf[k * 128 + c];   // [k][c] -> [c][k]
        wl1T[i] = (bf16_t)Wl1[k * 128 + c];
    }
    if (i < 384 * 128) {
        wih[i] = (bf16_t)Wih[i];
        whh[i] = (bf16_t)Whh[i];
    }
}

// ---------------- CSR build ----------------
__global__ void hist_kernel(const int* __restrict__ ei, int* __restrict__ deg, int nE) {
    int e = blockIdx.x * blockDim.x + threadIdx.x;
    if (e < nE) atomicAdd(&deg[ei[nE + e]], 1);
}

__global__ __launch_bounds__(SCAN_T) void scan1_kernel(
    const int* __restrict__ deg, int* __restrict__ rowptr, int* __restrict__ bsum, int n) {
    __shared__ int s[SCAN_T];
    int base = blockIdx.x * SCAN_CHUNK + threadIdx.x * SCAN_I;
    int v[SCAN_I];
    int sum = 0;
    for (int j = 0; j < SCAN_I; ++j) {
        int idx = base + j;
        v[j] = (idx < n) ? deg[idx] : 0;
        sum += v[j];
    }
    s[threadIdx.x] = sum;
    __syncthreads();
    for (int off = 1; off < SCAN_T; off <<= 1) {
        int t = (threadIdx.x >= off) ? s[threadIdx.x - off] : 0;
        __syncthreads();
        s[threadIdx.x] += t;
        __syncthreads();
    }
    int run = s[threadIdx.x] - sum;
    for (int j = 0; j < SCAN_I; ++j) {
        int idx = base + j;
        if (idx < n) rowptr[idx] = run;
        run += v[j];
    }
    if (threadIdx.x == SCAN_T - 1) bsum[blockIdx.x] = s[SCAN_T - 1];
}

__global__ __launch_bounds__(SCAN_T) void scan2_kernel(int* __restrict__ bsum, int nb) {
    __shared__ int s[SCAN_T];
    int v = (threadIdx.x < nb) ? bsum[threadIdx.x] : 0;
    s[threadIdx.x] = v;
    __syncthreads();
    for (int off = 1; off < SCAN_T; off <<= 1) {
        int t = (threadIdx.x >= off) ? s[threadIdx.x - off] : 0;
        __syncthreads();
        s[threadIdx.x] += t;
        __syncthreads();
    }
    if (threadIdx.x < nb) bsum[threadIdx.x] = s[threadIdx.x] - v;
}

__global__ void scan3_kernel(int* __restrict__ rowptr, int* __restrict__ cursor,
                             const int* __restrict__ bsum, int n, int nE) {
    int idx = blockIdx.x * blockDim.x + threadIdx.x;
    if (idx < n) {
        int val = rowptr[idx] + bsum[idx / SCAN_CHUNK];
        rowptr[idx] = val;
        cursor[idx] = val;
    }
    if (idx == 0) rowptr[n] = nE;
}

__global__ void scatter_kernel(const int* __restrict__ ei, const float* __restrict__ ew,
                               int* __restrict__ cursor, int2* __restrict__ srcw, int nE) {
    int e = blockIdx.x * blockDim.x + threadIdx.x;
    if (e < nE) {
        int src = ei[e], dst = ei[nE + e];
        float w = ew[e];
        int pos = atomicAdd(&cursor[dst], 1);
        srcw[pos] = make_int2(src, __float_as_int(w));
    }
}

// ---------------- gated conv via CSR: bf16 gather, bf16 write ----------------
__global__ __launch_bounds__(256) void conv_csr_kernel(
    const bf16_t* __restrict__ xb, const int* __restrict__ rowptr,
    const int2* __restrict__ srcw, bf16_t* __restrict__ agg, int n) {
    int lane = threadIdx.x & 63;
    int d = (blockIdx.x * blockDim.x + threadIdx.x) >> 6;
    if (d >= n) return;
    int beg = rowptr[d], end = rowptr[d + 1];
    float ax = 0.f, ay = 0.f;
    for (int e = beg; e < end; ++e) {
        int2 sw = srcw[e];
        int src = __builtin_amdgcn_readfirstlane(sw.x);
        float w = __int_as_float(__builtin_amdgcn_readfirstlane(sw.y));
        unsigned u = *(const unsigned*)(xb + (size_t)src * H + lane * 2);
        float vx = __uint_as_float(u << 16);
        float vy = __uint_as_float(u & 0xffff0000u);
        ax += vx * w;
        ay += vy * w;
    }
    bf16x2 r;
    r[0] = (bf16_t)ax; r[1] = (bf16_t)ay;
    *(bf16x2*)(agg + (size_t)d * H + lane * 2) = r;
}

// ---------------- first lin: A f32 -> out f32 + bf16 ----------------
__global__ __launch_bounds__(256) void lin_first_kernel(
    const float* __restrict__ A, const bf16_t* __restrict__ Bt,
    const float* __restrict__ bias, float* __restrict__ outf,
    bf16_t* __restrict__ outb, int n) {
    int wid = threadIdx.x >> 6, lane = threadIdx.x & 63;
    int r0 = (blockIdx.x * 4 + wid) * 32;
    if (r0 >= n) return;
    int lrow = lane & 15, lk8 = (lane >> 4) * 8;

    bf16x8 a[2][4];
    for (int rt = 0; rt < 2; ++rt) {
        int row = r0 + rt * 16 + lrow;
        if (row >= n) row = n - 1;
        for (int t = 0; t < 4; ++t) a[rt][t] = load_a_frag_f32(A, row, t * 32 + lk8);
    }
    for (int ct = 0; ct < 8; ++ct) {
        int c0 = ct * 16;
        f32x4 acc0 = {0.f, 0.f, 0.f, 0.f}, acc1 = {0.f, 0.f, 0.f, 0.f};
        const bf16_t* bp = Bt + (size_t)(c0 + lrow) * H + lk8;
        for (int t = 0; t < 4; ++t) {
            bf16x8 b = *(const bf16x8*)(bp + t * 32);
            acc0 = __builtin_amdgcn_mfma_f32_16x16x32_bf16(a[0][t], b, acc0, 0, 0, 0);
            acc1 = __builtin_amdgcn_mfma_f32_16x16x32_bf16(a[1][t], b, acc1, 0, 0, 0);
        }
        int col = c0 + lrow;
        float bv = bias[col];
        for (int r = 0; r < 4; ++r) {
            int row0 = r0 + (lane >> 4) * 4 + r;
            float v0 = acc0[r] + bv;
            if (row0 < n) { outf[(size_t)row0 * H + col] = v0; outb[(size_t)row0 * H + col] = (bf16_t)v0; }
            int row1 = row0 + 16;
            float v1 = acc1[r] + bv;
            if (row1 < n) { outf[(size_t)row1 * H + col] = v1; outb[(size_t)row1 * H + col] = (bf16_t)v1; }
        }
    }
}

// ---------------- mid lin: A bf16 -> out bf16 ----------------
__global__ __launch_bounds__(256) void lin_mid_kernel(
    const bf16_t* __restrict__ A, const bf16_t* __restrict__ Bt,
    const float* __restrict__ bias, bf16_t* __restrict__ out, int n) {
    int wid = threadIdx.x >> 6, lane = threadIdx.x & 63;
    int r0 = (blockIdx.x * 4 + wid) * 32;
    if (r0 >= n) return;
    int lrow = lane & 15, lk8 = (lane >> 4) * 8;

    bf16x8 a[2][4];
    for (int rt = 0; rt < 2; ++rt) {
        int row = r0 + rt * 16 + lrow;
        if (row >= n) row = n - 1;
        for (int t = 0; t < 4; ++t)
            a[rt][t] = *(const bf16x8*)(A + (size_t)row * H + t * 32 + lk8);
    }
    for (int ct = 0; ct < 8; ++ct) {
        int c0 = ct * 16;
        f32x4 acc0 = {0.f, 0.f, 0.f, 0.f}, acc1 = {0.f, 0.f, 0.f, 0.f};
        const bf16_t* bp = Bt + (size_t)(c0 + lrow) * H + lk8;
        for (int t = 0; t < 4; ++t) {
            bf16x8 b = *(const bf16x8*)(bp + t * 32);
            acc0 = __builtin_amdgcn_mfma_f32_16x16x32_bf16(a[0][t], b, acc0, 0, 0, 0);
            acc1 = __builtin_amdgcn_mfma_f32_16x16x32_bf16(a[1][t], b, acc1, 0, 0, 0);
        }
        int col = c0 + lrow;
        float bv = bias[col];
        for (int r = 0; r < 4; ++r) {
            int row0 = r0 + (lane >> 4) * 4 + r;
            if (row0 < n) out[(size_t)row0 * H + col] = (bf16_t)(acc0[r] + bv);
            int row1 = row0 + 16;
            if (row1 < n) out[(size_t)row1 * H + col] = (bf16_t)(acc1[r] + bv);
        }
    }
}

// ---------------- fused GRU cell (bf16 in, bf16 out or fused head) ----------------
template<bool LOGITS>
__global__ __launch_bounds__(256) void gru_kernel(
    const bf16_t* __restrict__ inp, const bf16_t* __restrict__ hidb,
    const float* __restrict__ hidf,
    const bf16_t* __restrict__ Wih, const bf16_t* __restrict__ Whh,
    const float* __restrict__ bih, const float* __restrict__ bhh,
    bf16_t* __restrict__ out, const float* __restrict__ Wo,
    const float* __restrict__ bo, float* __restrict__ logits, int n) {
    int wid = threadIdx.x >> 6, lane = threadIdx.x & 63;
    int r0 = (blockIdx.x * 4 + wid) * 32;
    if (r0 >= n) return;
    int lrow = lane & 15, lk8 = (lane >> 4) * 8;

    bf16x8 ai[2][4], ah[2][4];
    for (int rt = 0; rt < 2; ++rt) {
        int row = r0 + rt * 16 + lrow;
        if (row >= n) row = n - 1;
        for (int t = 0; t < 4; ++t) {
            ai[rt][t] = *(const bf16x8*)(inp  + (size_t)row * H + t * 32 + lk8);
            ah[rt][t] = *(const bf16x8*)(hidb + (size_t)row * H + t * 32 + lk8);
        }
    }

    float s0[2][4], s1[2][4];
    if (LOGITS) {
        for (int rt = 0; rt < 2; ++rt)
            for (int r = 0; r < 4; ++r) { s0[rt][r] = 0.f; s1[rt][r] = 0.f; }
    }

    for (int ct = 0; ct < 8; ++ct) {
        int c0 = ct * 16;
        int col = c0 + lrow;
        f32x4 air[2], aiz[2], ain[2], ahr[2], ahz[2], ahn[2];
        for (int rt = 0; rt < 2; ++rt) {
            air[rt] = (f32x4){0.f,0.f,0.f,0.f}; aiz[rt] = (f32x4){0.f,0.f,0.f,0.f};
            ain[rt] = (f32x4){0.f,0.f,0.f,0.f}; ahr[rt] = (f32x4){0.f,0.f,0.f,0.f};
            ahz[rt] = (f32x4){0.f,0.f,0.f,0.f}; ahn[rt] = (f32x4){0.f,0.f,0.f,0.f};
        }
        const bf16_t* pir = Wih + (size_t)(col)       * H + lk8;
        const bf16_t* piz = Wih + (size_t)(128 + col) * H + lk8;
        const bf16_t* pin = Wih + (size_t)(256 + col) * H + lk8;
        const bf16_t* phr = Whh + (size_t)(col)       * H + lk8;
        const bf16_t* phz = Whh + (size_t)(128 + col) * H + lk8;
        const bf16_t* phn = Whh + (size_t)(256 + col) * H + lk8;
        for (int t = 0; t < 4; ++t) {
            bf16x8 bir = *(const bf16x8*)(pir + t * 32);
            bf16x8 biz = *(const bf16x8*)(piz + t * 32);
            bf16x8 bin = *(const bf16x8*)(pin + t * 32);
            bf16x8 bhr = *(const bf16x8*)(phr + t * 32);
            bf16x8 bhz = *(const bf16x8*)(phz + t * 32);
            bf16x8 bhn = *(const bf16x8*)(phn + t * 32);
            for (int rt = 0; rt < 2; ++rt) {
                air[rt] = __builtin_amdgcn_mfma_f32_16x16x32_bf16(ai[rt][t], bir, air[rt], 0, 0, 0);
                aiz[rt] = __builtin_amdgcn_mfma_f32_16x16x32_bf16(ai[rt][t], biz, aiz[rt], 0, 0, 0);
                ain[rt] = __builtin_amdgcn_mfma_f32_16x16x32_bf16(ai[rt][t], bin, ain[rt], 0, 0, 0);
                ahr[rt] = __builtin_amdgcn_mfma_f32_16x16x32_bf16(ah[rt][t], bhr, ahr[rt], 0, 0, 0);
                ahz[rt] = __builtin_amdgcn_mfma_f32_16x16x32_bf16(ah[rt][t], bhz, ahz[rt], 0, 0, 0);
                ahn[rt] = __builtin_amdgcn_mfma_f32_16x16x32_bf16(ah[rt][t], bhn, ahn[rt], 0, 0, 0);
            }
        }
        float b_ir = bih[col], b_iz = bih[128 + col], b_in = bih[256 + col];
        float b_hr = bhh[col], b_hz = bhh[128 + col], b_hn = bhh[256 + col];
        float w0 = 0.f, w1 = 0.f;
        if (LOGITS) { float2 wv = *(const float2*)(Wo + col * 2); w0 = wv.x; w1 = wv.y; }
        for (int rt = 0; rt < 2; ++rt) {
            for (int r = 0; r < 4; ++r) {
                int row = r0 + rt * 16 + (lane >> 4) * 4 + r;
                float irv = air[rt][r] + b_ir, hrv = ahr[rt][r] + b_hr;
                float izv = aiz[rt][r] + b_iz, hzv = ahz[rt][r] + b_hz;
                float inv = ain[rt][r] + b_in, hnv = ahn[rt][r] + b_hn;
                float rg = 1.f / (1.f + __expf(-(irv + hrv)));
                float zg = 1.f / (1.f + __expf(-(izv + hzv)));
                float xx = inv + rg * hnv;
                float ng = 2.f / (1.f + __expf(-2.f * xx)) - 1.f;   // tanh
                bool ok = (row < n);
                float hv = ok ? hidf[(size_t)row * H + col] : 0.f;
                float hout = (1.f - zg) * ng + zg * hv;
                if (LOGITS) {
                    s0[rt][r] += hout * w0;
                    s1[rt][r] += hout * w1;
                } else if (ok) {
                    out[(size_t)row * H + col] = (bf16_t)hout;
                }
            }
        }
    }

    if (LOGITS) {
        // reduce over the 16 lanes sharing (lane>>4); they hold cols lane&15 + 16*ct
        for (int m = 1; m < 16; m <<= 1) {
            for (int rt = 0; rt < 2; ++rt)
                for (int r = 0; r < 4; ++r) {
                    s0[rt][r] += __shfl_xor(s0[rt][r], m);
                    s1[rt][r] += __shfl_xor(s1[rt][r], m);
                }
        }
        if ((lane & 15) == 0) {
            float bo0 = bo[0], bo1 = bo[1];
            for (int rt = 0; rt < 2; ++rt)
                for (int r = 0; r < 4; ++r) {
                    int row = r0 + rt * 16 + (lane >> 4) * 4 + r;
                    if (row < n) {
                        float l0 = s0[rt][r] + bo0, l1 = s1[rt][r] + bo1;
                        float mx = fmaxf(l0, l1);
                        float lse = mx + __logf(__expf(l0 - mx) + __expf(l1 - mx));
                        logits[(size_t)row * 2]     = l0 - lse;
                        logits[(size_t)row * 2 + 1] = l1 - lse;
                    }
                }
        }
    }
}

extern "C" void kernel_launch(void* const* d_in, const int* in_sizes, int n_in,
                              void* d_out, int out_size, void* d_ws, size_t ws_size,
                              hipStream_t stream) {
    const float* x   = (const float*)d_in[0];
    const int*   ei  = (const int*)d_in[1];
    const float* ew  = (const float*)d_in[2];
    const float* Wf  = (const float*)d_in[3];
    const float* bf  = (const float*)d_in[4];
    const float* Wih = (const float*)d_in[5];
    const float* bih = (const float*)d_in[6];
    const float* Whh = (const float*)d_in[7];
    const float* bhh = (const float*)d_in[8];
    const float* Wl1 = (const float*)d_in[9];
    const float* bl1 = (const float*)d_in[10];
    const float* Wo  = (const float*)d_in[11];
    const float* bo  = (const float*)d_in[12];

    int n  = in_sizes[0] / H;     // 100000
    int nE = in_sizes[2];         // 1600000

    float* hbuf   = (float*)d_ws;                         // [n][H] f32 hidden (for GRU blend)
    bf16_t* hbufb = (bf16_t*)(hbuf + (size_t)n * H);      // [n][H] bf16 hidden
    bf16_t* b1b   = hbufb + (size_t)n * H;                // [n][H] bf16: agg1 / g1 (in-place) / conv2-out
    bf16_t* b2b   = b1b + (size_t)n * H;                  // [n][H] bf16: lin1-out
    bf16_t* wfT   = b2b + (size_t)n * H;
    bf16_t* wih   = wfT + 128 * 128;
    bf16_t* whh   = wih + 384 * 128;
    bf16_t* wl1T  = whh + 384 * 128;
    int* deg    = (int*)(wl1T + 128 * 128);               // [n]
    int* rowptr = deg + n;                                // [n+1]
    int* cursor = rowptr + (n + 1);                       // [n]
    int2* srcw  = (int2*)((char*)(cursor + n) + ((size_t)(-(intptr_t)(cursor + n)) & 7)); // [nE]

    int gemmGrid = (n + 127) / 128;
    int nScanBlocks = (n + SCAN_CHUNK - 1) / SCAN_CHUNK;

    // ---- weights + CSR build ----
    prep_weights<<<192, 256, 0, stream>>>(Wf, Wih, Whh, Wl1, wfT, wih, whh, wl1T);
    hipMemsetAsync(deg, 0, (size_t)n * sizeof(int), stream);
    hist_kernel<<<(nE + 255) / 256, 256, 0, stream>>>(ei, deg, nE);
    scan1_kernel<<<nScanBlocks, SCAN_T, 0, stream>>>(deg, rowptr, cursor, n);
    scan2_kernel<<<1, SCAN_T, 0, stream>>>(cursor, nScanBlocks);
    scan3_kernel<<<(n + 255) / 256, 256, 0, stream>>>(rowptr, deg, cursor, n, nE);
    scatter_kernel<<<(nE + 255) / 256, 256, 0, stream>>>(ei, ew, deg, srcw, nE);

    // ---- pipeline ----
    lin_first_kernel<<<gemmGrid, 256, 0, stream>>>(x, wfT, bf, hbuf, hbufb, n);
    conv_csr_kernel<<<(n + 3) / 4, 256, 0, stream>>>(hbufb, rowptr, srcw, b1b, n);
    gru_kernel<false><<<gemmGrid, 256, 0, stream>>>(b1b, hbufb, hbuf, wih, whh, bih, bhh,
                                                    b1b, nullptr, nullptr, nullptr, n);
    lin_mid_kernel<<<gemmGrid, 256, 0, stream>>>(b1b, wl1T, bl1, b2b, n);
    conv_csr_kernel<<<(n + 3) / 4, 256, 0, stream>>>(b2b, rowptr, srcw, b1b, n);
    gru_kernel<true><<<gemmGrid, 256, 0, stream>>>(b1b, hbufb, hbuf, wih, whh, bih, bhh,
                                                   nullptr, Wo, bo, (float*)d_out, n);
}

// Round 4
// 610.622 us; speedup vs baseline: 4.8540x; 1.2971x over previous
//
#include <hip/hip_runtime.h>
#include <hip/hip_bf16.h>

#define H 128
#define SCAN_T 256
#define SCAN_I 8
#define SCAN_CHUNK (SCAN_T * SCAN_I)   // 2048 elems per scan block

typedef __bf16 bf16_t;
typedef __attribute__((ext_vector_type(2))) __bf16 bf16x2;
typedef __attribute__((ext_vector_type(8))) __bf16 bf16x8;
typedef __attribute__((ext_vector_type(4))) float f32x4;

static_assert(sizeof(bf16x8) == 16, "bf16x8 must be 16 bytes");

// f32 source -> A-fragment (8 bf16) for mfma_f32_16x16x32_bf16
__device__ inline bf16x8 load_a_frag_f32(const float* __restrict__ A, int row, int koff) {
    const float4* p = (const float4*)(A + (size_t)row * H + koff);
    float4 v0 = p[0], v1 = p[1];
    bf16x8 r;
    r[0] = (bf16_t)v0.x; r[1] = (bf16_t)v0.y; r[2] = (bf16_t)v0.z; r[3] = (bf16_t)v0.w;
    r[4] = (bf16_t)v1.x; r[5] = (bf16_t)v1.y; r[6] = (bf16_t)v1.z; r[7] = (bf16_t)v1.w;
    return r;
}

// ---------------- weight prep ----------------
__global__ void prep_weights(const float* __restrict__ Wf,  const float* __restrict__ Wih,
                             const float* __restrict__ Whh, const float* __restrict__ Wl1,
                             bf16_t* __restrict__ wfT, bf16_t* __restrict__ wih,
                             bf16_t* __restrict__ whh, bf16_t* __restrict__ wl1T) {
    int i = blockIdx.x * blockDim.x + threadIdx.x;
    if (i < 128 * 128) {
        int c = i >> 7, k = i & 127;
        wfT[i]  = (bf16_t)Wf[k * 128 + c];   // [k][c] -> [c][k]
        wl1T[i] = (bf16_t)Wl1[k * 128 + c];
    }
    if (i < 384 * 128) {
        wih[i] = (bf16_t)Wih[i];
        whh[i] = (bf16_t)Whh[i];
    }
}

// ---------------- CSR build ----------------
__global__ void hist_kernel(const int* __restrict__ ei, int* __restrict__ deg, int nE) {
    int e = blockIdx.x * blockDim.x + threadIdx.x;
    if (e < nE) atomicAdd(&deg[ei[nE + e]], 1);
}

__global__ __launch_bounds__(SCAN_T) void scan1_kernel(
    const int* __restrict__ deg, int* __restrict__ rowptr, int* __restrict__ bsum, int n) {
    __shared__ int s[SCAN_T];
    int base = blockIdx.x * SCAN_CHUNK + threadIdx.x * SCAN_I;
    int v[SCAN_I];
    int sum = 0;
    for (int j = 0; j < SCAN_I; ++j) {
        int idx = base + j;
        v[j] = (idx < n) ? deg[idx] : 0;
        sum += v[j];
    }
    s[threadIdx.x] = sum;
    __syncthreads();
    for (int off = 1; off < SCAN_T; off <<= 1) {
        int t = (threadIdx.x >= off) ? s[threadIdx.x - off] : 0;
        __syncthreads();
        s[threadIdx.x] += t;
        __syncthreads();
    }
    int run = s[threadIdx.x] - sum;
    for (int j = 0; j < SCAN_I; ++j) {
        int idx = base + j;
        if (idx < n) rowptr[idx] = run;
        run += v[j];
    }
    if (threadIdx.x == SCAN_T - 1) bsum[blockIdx.x] = s[SCAN_T - 1];
}

__global__ __launch_bounds__(SCAN_T) void scan2_kernel(int* __restrict__ bsum, int nb) {
    __shared__ int s[SCAN_T];
    int v = (threadIdx.x < nb) ? bsum[threadIdx.x] : 0;
    s[threadIdx.x] = v;
    __syncthreads();
    for (int off = 1; off < SCAN_T; off <<= 1) {
        int t = (threadIdx.x >= off) ? s[threadIdx.x - off] : 0;
        __syncthreads();
        s[threadIdx.x] += t;
        __syncthreads();
    }
    if (threadIdx.x < nb) bsum[threadIdx.x] = s[threadIdx.x] - v;
}

__global__ void scan3_kernel(int* __restrict__ rowptr, int* __restrict__ cursor,
                             const int* __restrict__ bsum, int n, int nE) {
    int idx = blockIdx.x * blockDim.x + threadIdx.x;
    if (idx < n) {
        int val = rowptr[idx] + bsum[idx / SCAN_CHUNK];
        rowptr[idx] = val;
        cursor[idx] = val;
    }
    if (idx == 0) rowptr[n] = nE;
}

__global__ void scatter_kernel(const int* __restrict__ ei, const float* __restrict__ ew,
                               int* __restrict__ cursor, int2* __restrict__ srcw, int nE) {
    int e = blockIdx.x * blockDim.x + threadIdx.x;
    if (e < nE) {
        int src = ei[e], dst = ei[nE + e];
        float w = ew[e];
        int pos = atomicAdd(&cursor[dst], 1);
        srcw[pos] = make_int2(src, __float_as_int(w));
    }
}

// ---------------- gated conv via CSR: 4 edges in flight per wave ----------------
__device__ inline void conv_fma(float* acc, uint4 u, float w) {
    acc[0] += __uint_as_float(u.x << 16) * w;
    acc[1] += __uint_as_float(u.x & 0xffff0000u) * w;
    acc[2] += __uint_as_float(u.y << 16) * w;
    acc[3] += __uint_as_float(u.y & 0xffff0000u) * w;
    acc[4] += __uint_as_float(u.z << 16) * w;
    acc[5] += __uint_as_float(u.z & 0xffff0000u) * w;
    acc[6] += __uint_as_float(u.w << 16) * w;
    acc[7] += __uint_as_float(u.w & 0xffff0000u) * w;
}

__global__ __launch_bounds__(256) void conv_csr_kernel(
    const bf16_t* __restrict__ xb, const int* __restrict__ rowptr,
    const int2* __restrict__ srcw, bf16_t* __restrict__ agg, int n) {
    int lane = threadIdx.x & 63;
    int d = (blockIdx.x * blockDim.x + threadIdx.x) >> 6;
    if (d >= n) return;
    int q = lane >> 4;        // edge slot 0..3
    int l = lane & 15;        // channel group: cols 8l..8l+7
    int beg = rowptr[d], end = rowptr[d + 1];

    float acc[8];
    #pragma unroll
    for (int i = 0; i < 8; ++i) acc[i] = 0.f;

    int e = beg + q;
    for (; e + 4 < end; e += 8) {          // two edges per iter -> 8 gathers in flight/wave
        int2 sw0 = srcw[e];
        int2 sw1 = srcw[e + 4];
        uint4 u0 = *(const uint4*)(xb + (size_t)sw0.x * H + l * 8);
        uint4 u1 = *(const uint4*)(xb + (size_t)sw1.x * H + l * 8);
        conv_fma(acc, u0, __int_as_float(sw0.y));
        conv_fma(acc, u1, __int_as_float(sw1.y));
    }
    if (e < end) {
        int2 sw = srcw[e];
        uint4 u = *(const uint4*)(xb + (size_t)sw.x * H + l * 8);
        conv_fma(acc, u, __int_as_float(sw.y));
    }

    // reduce across the 4 edge slots
    #pragma unroll
    for (int i = 0; i < 8; ++i) {
        acc[i] += __shfl_xor(acc[i], 16);
        acc[i] += __shfl_xor(acc[i], 32);
    }
    if (q == 0) {
        bf16x8 r;
        #pragma unroll
        for (int i = 0; i < 8; ++i) r[i] = (bf16_t)acc[i];
        *(bf16x8*)(agg + (size_t)d * H + l * 8) = r;
    }
}

// ---------------- first lin: A f32 -> out f32 + bf16 ----------------
__global__ __launch_bounds__(256) void lin_first_kernel(
    const float* __restrict__ A, const bf16_t* __restrict__ Bt,
    const float* __restrict__ bias, float* __restrict__ outf,
    bf16_t* __restrict__ outb, int n) {
    int wid = threadIdx.x >> 6, lane = threadIdx.x & 63;
    int r0 = (blockIdx.x * 4 + wid) * 32;
    if (r0 >= n) return;
    int lrow = lane & 15, lk8 = (lane >> 4) * 8;

    bf16x8 a[2][4];
    for (int rt = 0; rt < 2; ++rt) {
        int row = r0 + rt * 16 + lrow;
        if (row >= n) row = n - 1;
        for (int t = 0; t < 4; ++t) a[rt][t] = load_a_frag_f32(A, row, t * 32 + lk8);
    }
    for (int ct = 0; ct < 8; ++ct) {
        int c0 = ct * 16;
        f32x4 acc0 = {0.f, 0.f, 0.f, 0.f}, acc1 = {0.f, 0.f, 0.f, 0.f};
        const bf16_t* bp = Bt + (size_t)(c0 + lrow) * H + lk8;
        for (int t = 0; t < 4; ++t) {
            bf16x8 b = *(const bf16x8*)(bp + t * 32);
            acc0 = __builtin_amdgcn_mfma_f32_16x16x32_bf16(a[0][t], b, acc0, 0, 0, 0);
            acc1 = __builtin_amdgcn_mfma_f32_16x16x32_bf16(a[1][t], b, acc1, 0, 0, 0);
        }
        int col = c0 + lrow;
        float bv = bias[col];
        for (int r = 0; r < 4; ++r) {
            int row0 = r0 + (lane >> 4) * 4 + r;
            float v0 = acc0[r] + bv;
            if (row0 < n) { outf[(size_t)row0 * H + col] = v0; outb[(size_t)row0 * H + col] = (bf16_t)v0; }
            int row1 = row0 + 16;
            float v1 = acc1[r] + bv;
            if (row1 < n) { outf[(size_t)row1 * H + col] = v1; outb[(size_t)row1 * H + col] = (bf16_t)v1; }
        }
    }
}

// ---------------- mid lin: A bf16 -> out bf16 ----------------
__global__ __launch_bounds__(256) void lin_mid_kernel(
    const bf16_t* __restrict__ A, const bf16_t* __restrict__ Bt,
    const float* __restrict__ bias, bf16_t* __restrict__ out, int n) {
    int wid = threadIdx.x >> 6, lane = threadIdx.x & 63;
    int r0 = (blockIdx.x * 4 + wid) * 32;
    if (r0 >= n) return;
    int lrow = lane & 15, lk8 = (lane >> 4) * 8;

    bf16x8 a[2][4];
    for (int rt = 0; rt < 2; ++rt) {
        int row = r0 + rt * 16 + lrow;
        if (row >= n) row = n - 1;
        for (int t = 0; t < 4; ++t)
            a[rt][t] = *(const bf16x8*)(A + (size_t)row * H + t * 32 + lk8);
    }
    for (int ct = 0; ct < 8; ++ct) {
        int c0 = ct * 16;
        f32x4 acc0 = {0.f, 0.f, 0.f, 0.f}, acc1 = {0.f, 0.f, 0.f, 0.f};
        const bf16_t* bp = Bt + (size_t)(c0 + lrow) * H + lk8;
        for (int t = 0; t < 4; ++t) {
            bf16x8 b = *(const bf16x8*)(bp + t * 32);
            acc0 = __builtin_amdgcn_mfma_f32_16x16x32_bf16(a[0][t], b, acc0, 0, 0, 0);
            acc1 = __builtin_amdgcn_mfma_f32_16x16x32_bf16(a[1][t], b, acc1, 0, 0, 0);
        }
        int col = c0 + lrow;
        float bv = bias[col];
        for (int r = 0; r < 4; ++r) {
            int row0 = r0 + (lane >> 4) * 4 + r;
            if (row0 < n) out[(size_t)row0 * H + col] = (bf16_t)(acc0[r] + bv);
            int row1 = row0 + 16;
            if (row1 < n) out[(size_t)row1 * H + col] = (bf16_t)(acc1[r] + bv);
        }
    }
}

// ---------------- fused GRU cell (bf16 in, bf16 out or fused head) ----------------
template<bool LOGITS>
__global__ __launch_bounds__(256) void gru_kernel(
    const bf16_t* __restrict__ inp, const bf16_t* __restrict__ hidb,
    const float* __restrict__ hidf,
    const bf16_t* __restrict__ Wih, const bf16_t* __restrict__ Whh,
    const float* __restrict__ bih, const float* __restrict__ bhh,
    bf16_t* __restrict__ out, const float* __restrict__ Wo,
    const float* __restrict__ bo, float* __restrict__ logits, int n) {
    int wid = threadIdx.x >> 6, lane = threadIdx.x & 63;
    int r0 = (blockIdx.x * 4 + wid) * 32;
    if (r0 >= n) return;
    int lrow = lane & 15, lk8 = (lane >> 4) * 8;

    bf16x8 ai[2][4], ah[2][4];
    for (int rt = 0; rt < 2; ++rt) {
        int row = r0 + rt * 16 + lrow;
        if (row >= n) row = n - 1;
        for (int t = 0; t < 4; ++t) {
            ai[rt][t] = *(const bf16x8*)(inp  + (size_t)row * H + t * 32 + lk8);
            ah[rt][t] = *(const bf16x8*)(hidb + (size_t)row * H + t * 32 + lk8);
        }
    }

    float s0[2][4], s1[2][4];
    if (LOGITS) {
        for (int rt = 0; rt < 2; ++rt)
            for (int r = 0; r < 4; ++r) { s0[rt][r] = 0.f; s1[rt][r] = 0.f; }
    }

    for (int ct = 0; ct < 8; ++ct) {
        int c0 = ct * 16;
        int col = c0 + lrow;
        f32x4 air[2], aiz[2], ain[2], ahr[2], ahz[2], ahn[2];
        for (int rt = 0; rt < 2; ++rt) {
            air[rt] = (f32x4){0.f,0.f,0.f,0.f}; aiz[rt] = (f32x4){0.f,0.f,0.f,0.f};
            ain[rt] = (f32x4){0.f,0.f,0.f,0.f}; ahr[rt] = (f32x4){0.f,0.f,0.f,0.f};
            ahz[rt] = (f32x4){0.f,0.f,0.f,0.f}; ahn[rt] = (f32x4){0.f,0.f,0.f,0.f};
        }
        const bf16_t* pir = Wih + (size_t)(col)       * H + lk8;
        const bf16_t* piz = Wih + (size_t)(128 + col) * H + lk8;
        const bf16_t* pin = Wih + (size_t)(256 + col) * H + lk8;
        const bf16_t* phr = Whh + (size_t)(col)       * H + lk8;
        const bf16_t* phz = Whh + (size_t)(128 + col) * H + lk8;
        const bf16_t* phn = Whh + (size_t)(256 + col) * H + lk8;
        for (int t = 0; t < 4; ++t) {
            bf16x8 bir = *(const bf16x8*)(pir + t * 32);
            bf16x8 biz = *(const bf16x8*)(piz + t * 32);
            bf16x8 bin = *(const bf16x8*)(pin + t * 32);
            bf16x8 bhr = *(const bf16x8*)(phr + t * 32);
            bf16x8 bhz = *(const bf16x8*)(phz + t * 32);
            bf16x8 bhn = *(const bf16x8*)(phn + t * 32);
            for (int rt = 0; rt < 2; ++rt) {
                air[rt] = __builtin_amdgcn_mfma_f32_16x16x32_bf16(ai[rt][t], bir, air[rt], 0, 0, 0);
                aiz[rt] = __builtin_amdgcn_mfma_f32_16x16x32_bf16(ai[rt][t], biz, aiz[rt], 0, 0, 0);
                ain[rt] = __builtin_amdgcn_mfma_f32_16x16x32_bf16(ai[rt][t], bin, ain[rt], 0, 0, 0);
                ahr[rt] = __builtin_amdgcn_mfma_f32_16x16x32_bf16(ah[rt][t], bhr, ahr[rt], 0, 0, 0);
                ahz[rt] = __builtin_amdgcn_mfma_f32_16x16x32_bf16(ah[rt][t], bhz, ahz[rt], 0, 0, 0);
                ahn[rt] = __builtin_amdgcn_mfma_f32_16x16x32_bf16(ah[rt][t], bhn, ahn[rt], 0, 0, 0);
            }
        }
        float b_ir = bih[col], b_iz = bih[128 + col], b_in = bih[256 + col];
        float b_hr = bhh[col], b_hz = bhh[128 + col], b_hn = bhh[256 + col];
        float w0 = 0.f, w1 = 0.f;
        if (LOGITS) { float2 wv = *(const float2*)(Wo + col * 2); w0 = wv.x; w1 = wv.y; }
        for (int rt = 0; rt < 2; ++rt) {
            for (int r = 0; r < 4; ++r) {
                int row = r0 + rt * 16 + (lane >> 4) * 4 + r;
                float irv = air[rt][r] + b_ir, hrv = ahr[rt][r] + b_hr;
                float izv = aiz[rt][r] + b_iz, hzv = ahz[rt][r] + b_hz;
                float inv = ain[rt][r] + b_in, hnv = ahn[rt][r] + b_hn;
                float rg = 1.f / (1.f + __expf(-(irv + hrv)));
                float zg = 1.f / (1.f + __expf(-(izv + hzv)));
                float xx = inv + rg * hnv;
                float ng = 2.f / (1.f + __expf(-2.f * xx)) - 1.f;   // tanh
                bool ok = (row < n);
                float hv = ok ? hidf[(size_t)row * H + col] : 0.f;
                float hout = (1.f - zg) * ng + zg * hv;
                if (LOGITS) {
                    s0[rt][r] += hout * w0;
                    s1[rt][r] += hout * w1;
                } else if (ok) {
                    out[(size_t)row * H + col] = (bf16_t)hout;
                }
            }
        }
    }

    if (LOGITS) {
        for (int m = 1; m < 16; m <<= 1) {
            for (int rt = 0; rt < 2; ++rt)
                for (int r = 0; r < 4; ++r) {
                    s0[rt][r] += __shfl_xor(s0[rt][r], m);
                    s1[rt][r] += __shfl_xor(s1[rt][r], m);
                }
        }
        if ((lane & 15) == 0) {
            float bo0 = bo[0], bo1 = bo[1];
            for (int rt = 0; rt < 2; ++rt)
                for (int r = 0; r < 4; ++r) {
                    int row = r0 + rt * 16 + (lane >> 4) * 4 + r;
                    if (row < n) {
                        float l0 = s0[rt][r] + bo0, l1 = s1[rt][r] + bo1;
                        float mx = fmaxf(l0, l1);
                        float lse = mx + __logf(__expf(l0 - mx) + __expf(l1 - mx));
                        logits[(size_t)row * 2]     = l0 - lse;
                        logits[(size_t)row * 2 + 1] = l1 - lse;
                    }
                }
        }
    }
}

extern "C" void kernel_launch(void* const* d_in, const int* in_sizes, int n_in,
                              void* d_out, int out_size, void* d_ws, size_t ws_size,
                              hipStream_t stream) {
    const float* x   = (const float*)d_in[0];
    const int*   ei  = (const int*)d_in[1];
    const float* ew  = (const float*)d_in[2];
    const float* Wf  = (const float*)d_in[3];
    const float* bf  = (const float*)d_in[4];
    const float* Wih = (const float*)d_in[5];
    const float* bih = (const float*)d_in[6];
    const float* Whh = (const float*)d_in[7];
    const float* bhh = (const float*)d_in[8];
    const float* Wl1 = (const float*)d_in[9];
    const float* bl1 = (const float*)d_in[10];
    const float* Wo  = (const float*)d_in[11];
    const float* bo  = (const float*)d_in[12];

    int n  = in_sizes[0] / H;     // 100000
    int nE = in_sizes[2];         // 1600000

    float* hbuf   = (float*)d_ws;                         // [n][H] f32 hidden (GRU blend)
    bf16_t* hbufb = (bf16_t*)(hbuf + (size_t)n * H);      // [n][H] bf16 hidden
    bf16_t* b1b   = hbufb + (size_t)n * H;                // [n][H] bf16
    bf16_t* b2b   = b1b + (size_t)n * H;                  // [n][H] bf16
    bf16_t* wfT   = b2b + (size_t)n * H;
    bf16_t* wih   = wfT + 128 * 128;
    bf16_t* whh   = wih + 384 * 128;
    bf16_t* wl1T  = whh + 384 * 128;
    int* deg    = (int*)(wl1T + 128 * 128);               // [n]
    int* rowptr = deg + n;                                // [n+1]
    int* cursor = rowptr + (n + 1);                       // [n]
    int2* srcw  = (int2*)((char*)(cursor + n) + ((size_t)(-(intptr_t)(cursor + n)) & 7)); // [nE]

    int gemmGrid = (n + 127) / 128;
    int nScanBlocks = (n + SCAN_CHUNK - 1) / SCAN_CHUNK;

    // ---- weights + CSR build ----
    prep_weights<<<192, 256, 0, stream>>>(Wf, Wih, Whh, Wl1, wfT, wih, whh, wl1T);
    hipMemsetAsync(deg, 0, (size_t)n * sizeof(int), stream);
    hist_kernel<<<(nE + 255) / 256, 256, 0, stream>>>(ei, deg, nE);
    scan1_kernel<<<nScanBlocks, SCAN_T, 0, stream>>>(deg, rowptr, cursor, n);
    scan2_kernel<<<1, SCAN_T, 0, stream>>>(cursor, nScanBlocks);
    scan3_kernel<<<(n + 255) / 256, 256, 0, stream>>>(rowptr, deg, cursor, n, nE);
    scatter_kernel<<<(nE + 255) / 256, 256, 0, stream>>>(ei, ew, deg, srcw, nE);

    // ---- pipeline ----
    lin_first_kernel<<<gemmGrid, 256, 0, stream>>>(x, wfT, bf, hbuf, hbufb, n);
    conv_csr_kernel<<<(n + 3) / 4, 256, 0, stream>>>(hbufb, rowptr, srcw, b1b, n);
    gru_kernel<false><<<gemmGrid, 256, 0, stream>>>(b1b, hbufb, hbuf, wih, whh, bih, bhh,
                                                    b1b, nullptr, nullptr, nullptr, n);
    lin_mid_kernel<<<gemmGrid, 256, 0, stream>>>(b1b, wl1T, bl1, b2b, n);
    conv_csr_kernel<<<(n + 3) / 4, 256, 0, stream>>>(b2b, rowptr, srcw, b1b, n);
    gru_kernel<true><<<gemmGrid, 256, 0, stream>>>(b1b, hbufb, hbuf, wih, whh, bih, bhh,
                                                   nullptr, Wo, bo, (float*)d_out, n);
}

// Round 5
// 539.107 us; speedup vs baseline: 5.4979x; 1.1327x over previous
//
#include <hip/hip_runtime.h>
#include <hip/hip_bf16.h>

#define H 128
#define SCAN_T 256
#define SCAN_I 8
#define SCAN_CHUNK (SCAN_T * SCAN_I)   // 2048 elems per scan block

typedef __bf16 bf16_t;
typedef __attribute__((ext_vector_type(2))) __bf16 bf16x2;
typedef __attribute__((ext_vector_type(8))) __bf16 bf16x8;
typedef __attribute__((ext_vector_type(4))) float f32x4;

static_assert(sizeof(bf16x8) == 16, "bf16x8 must be 16 bytes");

// f32 source -> A-fragment (8 bf16) for mfma_f32_16x16x32_bf16
__device__ inline bf16x8 load_a_frag_f32(const float* __restrict__ A, int row, int koff) {
    const float4* p = (const float4*)(A + (size_t)row * H + koff);
    float4 v0 = p[0], v1 = p[1];
    bf16x8 r;
    r[0] = (bf16_t)v0.x; r[1] = (bf16_t)v0.y; r[2] = (bf16_t)v0.z; r[3] = (bf16_t)v0.w;
    r[4] = (bf16_t)v1.x; r[5] = (bf16_t)v1.y; r[6] = (bf16_t)v1.z; r[7] = (bf16_t)v1.w;
    return r;
}

// ---------------- weight prep ----------------
__global__ void prep_weights(const float* __restrict__ Wf,  const float* __restrict__ Wih,
                             const float* __restrict__ Whh, const float* __restrict__ Wl1,
                             bf16_t* __restrict__ wfT, bf16_t* __restrict__ wih,
                             bf16_t* __restrict__ whh, bf16_t* __restrict__ wl1T) {
    int i = blockIdx.x * blockDim.x + threadIdx.x;
    if (i < 128 * 128) {
        int c = i >> 7, k = i & 127;
        wfT[i]  = (bf16_t)Wf[k * 128 + c];   // [k][c] -> [c][k]
        wl1T[i] = (bf16_t)Wl1[k * 128 + c];
    }
    if (i < 384 * 128) {
        wih[i] = (bf16_t)Wih[i];
        whh[i] = (bf16_t)Whh[i];
    }
}

// ---------------- CSR build ----------------
__global__ void hist_kernel(const int* __restrict__ ei, int* __restrict__ deg, int nE) {
    int e = blockIdx.x * blockDim.x + threadIdx.x;
    if (e < nE) atomicAdd(&deg[ei[nE + e]], 1);
}

__global__ __launch_bounds__(SCAN_T) void scan1_kernel(
    const int* __restrict__ deg, int* __restrict__ rowptr, int* __restrict__ bsum, int n) {
    __shared__ int s[SCAN_T];
    int base = blockIdx.x * SCAN_CHUNK + threadIdx.x * SCAN_I;
    int v[SCAN_I];
    int sum = 0;
    for (int j = 0; j < SCAN_I; ++j) {
        int idx = base + j;
        v[j] = (idx < n) ? deg[idx] : 0;
        sum += v[j];
    }
    s[threadIdx.x] = sum;
    __syncthreads();
    for (int off = 1; off < SCAN_T; off <<= 1) {
        int t = (threadIdx.x >= off) ? s[threadIdx.x - off] : 0;
        __syncthreads();
        s[threadIdx.x] += t;
        __syncthreads();
    }
    int run = s[threadIdx.x] - sum;
    for (int j = 0; j < SCAN_I; ++j) {
        int idx = base + j;
        if (idx < n) rowptr[idx] = run;
        run += v[j];
    }
    if (threadIdx.x == SCAN_T - 1) bsum[blockIdx.x] = s[SCAN_T - 1];
}

__global__ __launch_bounds__(SCAN_T) void scan2_kernel(int* __restrict__ bsum, int nb) {
    __shared__ int s[SCAN_T];
    int v = (threadIdx.x < nb) ? bsum[threadIdx.x] : 0;
    s[threadIdx.x] = v;
    __syncthreads();
    for (int off = 1; off < SCAN_T; off <<= 1) {
        int t = (threadIdx.x >= off) ? s[threadIdx.x - off] : 0;
        __syncthreads();
        s[threadIdx.x] += t;
        __syncthreads();
    }
    if (threadIdx.x < nb) bsum[threadIdx.x] = s[threadIdx.x] - v;
}

__global__ void scan3_kernel(int* __restrict__ rowptr, int* __restrict__ cursor,
                             const int* __restrict__ bsum, int n, int nE) {
    int idx = blockIdx.x * blockDim.x + threadIdx.x;
    if (idx < n) {
        int val = rowptr[idx] + bsum[idx / SCAN_CHUNK];
        rowptr[idx] = val;
        cursor[idx] = val;
    }
    if (idx == 0) rowptr[n] = nE;
}

__global__ void scatter_kernel(const int* __restrict__ ei, const float* __restrict__ ew,
                               int* __restrict__ cursor, int2* __restrict__ srcw, int nE) {
    int e = blockIdx.x * blockDim.x + threadIdx.x;
    if (e < nE) {
        int src = ei[e], dst = ei[nE + e];
        float w = ew[e];
        int pos = atomicAdd(&cursor[dst], 1);
        srcw[pos] = make_int2(src, __float_as_int(w));
    }
}

// ---------------- gated conv via CSR: 4 edges in flight per wave ----------------
__device__ inline void conv_fma(float* acc, uint4 u, float w) {
    acc[0] += __uint_as_float(u.x << 16) * w;
    acc[1] += __uint_as_float(u.x & 0xffff0000u) * w;
    acc[2] += __uint_as_float(u.y << 16) * w;
    acc[3] += __uint_as_float(u.y & 0xffff0000u) * w;
    acc[4] += __uint_as_float(u.z << 16) * w;
    acc[5] += __uint_as_float(u.z & 0xffff0000u) * w;
    acc[6] += __uint_as_float(u.w << 16) * w;
    acc[7] += __uint_as_float(u.w & 0xffff0000u) * w;
}

__global__ __launch_bounds__(256) void conv_csr_kernel(
    const bf16_t* __restrict__ xb, const int* __restrict__ rowptr,
    const int2* __restrict__ srcw, bf16_t* __restrict__ agg, int n) {
    int lane = threadIdx.x & 63;
    int d = (blockIdx.x * blockDim.x + threadIdx.x) >> 6;
    if (d >= n) return;
    int q = lane >> 4;        // edge slot 0..3
    int l = lane & 15;        // channel group: cols 8l..8l+7
    int beg = rowptr[d], end = rowptr[d + 1];

    float acc[8];
    #pragma unroll
    for (int i = 0; i < 8; ++i) acc[i] = 0.f;

    int e = beg + q;
    for (; e + 4 < end; e += 8) {          // two edges per iter -> 8 gathers in flight/wave
        int2 sw0 = srcw[e];
        int2 sw1 = srcw[e + 4];
        uint4 u0 = *(const uint4*)(xb + (size_t)sw0.x * H + l * 8);
        uint4 u1 = *(const uint4*)(xb + (size_t)sw1.x * H + l * 8);
        conv_fma(acc, u0, __int_as_float(sw0.y));
        conv_fma(acc, u1, __int_as_float(sw1.y));
    }
    if (e < end) {
        int2 sw = srcw[e];
        uint4 u = *(const uint4*)(xb + (size_t)sw.x * H + l * 8);
        conv_fma(acc, u, __int_as_float(sw.y));
    }

    // reduce across the 4 edge slots
    #pragma unroll
    for (int i = 0; i < 8; ++i) {
        acc[i] += __shfl_xor(acc[i], 16);
        acc[i] += __shfl_xor(acc[i], 32);
    }
    if (q == 0) {
        bf16x8 r;
        #pragma unroll
        for (int i = 0; i < 8; ++i) r[i] = (bf16_t)acc[i];
        *(bf16x8*)(agg + (size_t)d * H + l * 8) = r;
    }
}

// ---------------- lin kernels: whole 32KB weight staged in LDS (swizzled) ----------------
// Swizzle: 16B granule at (row, seg) -> byte row*256 + ((seg*16) ^ ((row&7)<<4))

// first lin: A f32 -> out f32 + bf16
__global__ __launch_bounds__(256) void lin_first_kernel(
    const float* __restrict__ A, const bf16_t* __restrict__ Bt,
    const float* __restrict__ bias, float* __restrict__ outf,
    bf16_t* __restrict__ outb, int n) {
    __shared__ __align__(16) unsigned char wlds[32768];
    int tid = threadIdx.x;
    int wid = tid >> 6, lane = tid & 63;
    int r0 = (blockIdx.x * 4 + wid) * 32;
    int lrow = lane & 15, lq = lane >> 4, lk8 = lq * 8;

    #pragma unroll
    for (int i = 0; i < 8; ++i) {
        int g = i * 256 + tid;
        int row = g >> 4, seg = g & 15;
        uint4 v = *(const uint4*)(Bt + row * 128 + seg * 8);
        *(uint4*)(&wlds[row * 256 + ((seg * 16) ^ ((row & 7) << 4))]) = v;
    }

    bf16x8 a[2][4];
    for (int rt = 0; rt < 2; ++rt) {
        int row = r0 + rt * 16 + lrow;
        if (row >= n) row = n - 1;
        for (int t = 0; t < 4; ++t) a[rt][t] = load_a_frag_f32(A, row, t * 32 + lk8);
    }
    __syncthreads();

    for (int ct = 0; ct < 8; ++ct) {
        int c0 = ct * 16;
        f32x4 acc0 = {0.f, 0.f, 0.f, 0.f}, acc1 = {0.f, 0.f, 0.f, 0.f};
        int rbase = (c0 + lrow) * 256;
        int sw = (lrow & 7) << 4;
        #pragma unroll
        for (int t = 0; t < 4; ++t) {
            bf16x8 b = *(const bf16x8*)(&wlds[rbase + ((t * 64 + lq * 16) ^ sw)]);
            acc0 = __builtin_amdgcn_mfma_f32_16x16x32_bf16(a[0][t], b, acc0, 0, 0, 0);
            acc1 = __builtin_amdgcn_mfma_f32_16x16x32_bf16(a[1][t], b, acc1, 0, 0, 0);
        }
        int col = c0 + lrow;
        float bv = bias[col];
        for (int r = 0; r < 4; ++r) {
            int row0 = r0 + lq * 4 + r;
            float v0 = acc0[r] + bv;
            if (row0 < n) { outf[(size_t)row0 * H + col] = v0; outb[(size_t)row0 * H + col] = (bf16_t)v0; }
            int row1 = row0 + 16;
            float v1 = acc1[r] + bv;
            if (row1 < n) { outf[(size_t)row1 * H + col] = v1; outb[(size_t)row1 * H + col] = (bf16_t)v1; }
        }
    }
}

// mid lin: A bf16 -> out bf16
__global__ __launch_bounds__(256) void lin_mid_kernel(
    const bf16_t* __restrict__ A, const bf16_t* __restrict__ Bt,
    const float* __restrict__ bias, bf16_t* __restrict__ out, int n) {
    __shared__ __align__(16) unsigned char wlds[32768];
    int tid = threadIdx.x;
    int wid = tid >> 6, lane = tid & 63;
    int r0 = (blockIdx.x * 4 + wid) * 32;
    int lrow = lane & 15, lq = lane >> 4, lk8 = lq * 8;

    #pragma unroll
    for (int i = 0; i < 8; ++i) {
        int g = i * 256 + tid;
        int row = g >> 4, seg = g & 15;
        uint4 v = *(const uint4*)(Bt + row * 128 + seg * 8);
        *(uint4*)(&wlds[row * 256 + ((seg * 16) ^ ((row & 7) << 4))]) = v;
    }

    bf16x8 a[2][4];
    for (int rt = 0; rt < 2; ++rt) {
        int row = r0 + rt * 16 + lrow;
        if (row >= n) row = n - 1;
        for (int t = 0; t < 4; ++t)
            a[rt][t] = *(const bf16x8*)(A + (size_t)row * H + t * 32 + lk8);
    }
    __syncthreads();

    for (int ct = 0; ct < 8; ++ct) {
        int c0 = ct * 16;
        f32x4 acc0 = {0.f, 0.f, 0.f, 0.f}, acc1 = {0.f, 0.f, 0.f, 0.f};
        int rbase = (c0 + lrow) * 256;
        int sw = (lrow & 7) << 4;
        #pragma unroll
        for (int t = 0; t < 4; ++t) {
            bf16x8 b = *(const bf16x8*)(&wlds[rbase + ((t * 64 + lq * 16) ^ sw)]);
            acc0 = __builtin_amdgcn_mfma_f32_16x16x32_bf16(a[0][t], b, acc0, 0, 0, 0);
            acc1 = __builtin_amdgcn_mfma_f32_16x16x32_bf16(a[1][t], b, acc1, 0, 0, 0);
        }
        int col = c0 + lrow;
        float bv = bias[col];
        for (int r = 0; r < 4; ++r) {
            int row0 = r0 + lq * 4 + r;
            if (row0 < n) out[(size_t)row0 * H + col] = (bf16_t)(acc0[r] + bv);
            int row1 = row0 + 16;
            if (row1 < n) out[(size_t)row1 * H + col] = (bf16_t)(acc1[r] + bv);
        }
    }
}

// ---------------- fused GRU cell: double-buffered LDS weight staging ----------------
template<bool LOGITS>
__global__ __launch_bounds__(256) void gru_kernel(
    const bf16_t* __restrict__ inp, const bf16_t* __restrict__ hidb,
    const float* __restrict__ hidf,
    const bf16_t* __restrict__ Wih, const bf16_t* __restrict__ Whh,
    const float* __restrict__ bih, const float* __restrict__ bhh,
    bf16_t* __restrict__ out, const float* __restrict__ Wo,
    const float* __restrict__ bo, float* __restrict__ logits, int n) {
    __shared__ __align__(16) unsigned char wlds[2][6 * 4096];
    int tid = threadIdx.x;
    int wid = tid >> 6, lane = tid & 63;
    int r0 = (blockIdx.x * 4 + wid) * 32;
    int lrow = lane & 15, lq = lane >> 4, lk8 = lq * 8;

    // staging geometry: thread covers one 16B granule per slab
    int srow = tid >> 4;                              // 0..15 (slab row = col within ct)
    int sseg = tid & 15;                              // 0..15 granule in row
    int s_src_off = srow * 128 + sseg * 8;            // element offset in [16][128] slab
    int s_lds_off = srow * 256 + ((sseg * 16) ^ ((srow & 7) << 4));

    uint4 streg[6];
    auto stage_load = [&](int ct) {
        const bf16_t* b0 = Wih + (size_t)(ct * 16) * 128;
        const bf16_t* b1 = Wih + (size_t)(128 + ct * 16) * 128;
        const bf16_t* b2 = Wih + (size_t)(256 + ct * 16) * 128;
        const bf16_t* b3 = Whh + (size_t)(ct * 16) * 128;
        const bf16_t* b4 = Whh + (size_t)(128 + ct * 16) * 128;
        const bf16_t* b5 = Whh + (size_t)(256 + ct * 16) * 128;
        streg[0] = *(const uint4*)(b0 + s_src_off);
        streg[1] = *(const uint4*)(b1 + s_src_off);
        streg[2] = *(const uint4*)(b2 + s_src_off);
        streg[3] = *(const uint4*)(b3 + s_src_off);
        streg[4] = *(const uint4*)(b4 + s_src_off);
        streg[5] = *(const uint4*)(b5 + s_src_off);
    };
    auto stage_write = [&](int buf) {
        #pragma unroll
        for (int s = 0; s < 6; ++s)
            *(uint4*)(&wlds[buf][s * 4096 + s_lds_off]) = streg[s];
    };

    // A fragments in registers (clamped rows; stores guarded below)
    bf16x8 ai[2][4], ah[2][4];
    for (int rt = 0; rt < 2; ++rt) {
        int row = r0 + rt * 16 + lrow;
        if (row >= n) row = n - 1;
        for (int t = 0; t < 4; ++t) {
            ai[rt][t] = *(const bf16x8*)(inp  + (size_t)row * H + t * 32 + lk8);
            ah[rt][t] = *(const bf16x8*)(hidb + (size_t)row * H + t * 32 + lk8);
        }
    }

    stage_load(0);
    stage_write(0);
    __syncthreads();

    float s0[2][4], s1[2][4];
    if (LOGITS) {
        for (int rt = 0; rt < 2; ++rt)
            for (int r = 0; r < 4; ++r) { s0[rt][r] = 0.f; s1[rt][r] = 0.f; }
    }

    for (int ct = 0; ct < 8; ++ct) {
        if (ct + 1 < 8) stage_load(ct + 1);
        const unsigned char* wb = wlds[ct & 1];
        int col = ct * 16 + lrow;

        f32x4 air[2], aiz[2], ain[2], ahr[2], ahz[2], ahn[2];
        for (int rt = 0; rt < 2; ++rt) {
            air[rt] = (f32x4){0.f,0.f,0.f,0.f}; aiz[rt] = (f32x4){0.f,0.f,0.f,0.f};
            ain[rt] = (f32x4){0.f,0.f,0.f,0.f}; ahr[rt] = (f32x4){0.f,0.f,0.f,0.f};
            ahz[rt] = (f32x4){0.f,0.f,0.f,0.f}; ahn[rt] = (f32x4){0.f,0.f,0.f,0.f};
        }
        int rbase = lrow * 256;
        int sw = (lrow & 7) << 4;
        #pragma unroll
        for (int t = 0; t < 4; ++t) {
            int roff = rbase + ((t * 64 + lq * 16) ^ sw);
            bf16x8 bir = *(const bf16x8*)(wb + 0 * 4096 + roff);
            bf16x8 biz = *(const bf16x8*)(wb + 1 * 4096 + roff);
            bf16x8 bin = *(const bf16x8*)(wb + 2 * 4096 + roff);
            bf16x8 bhr = *(const bf16x8*)(wb + 3 * 4096 + roff);
            bf16x8 bhz = *(const bf16x8*)(wb + 4 * 4096 + roff);
            bf16x8 bhn = *(const bf16x8*)(wb + 5 * 4096 + roff);
            for (int rt = 0; rt < 2; ++rt) {
                air[rt] = __builtin_amdgcn_mfma_f32_16x16x32_bf16(ai[rt][t], bir, air[rt], 0, 0, 0);
                aiz[rt] = __builtin_amdgcn_mfma_f32_16x16x32_bf16(ai[rt][t], biz, aiz[rt], 0, 0, 0);
                ain[rt] = __builtin_amdgcn_mfma_f32_16x16x32_bf16(ai[rt][t], bin, ain[rt], 0, 0, 0);
                ahr[rt] = __builtin_amdgcn_mfma_f32_16x16x32_bf16(ah[rt][t], bhr, ahr[rt], 0, 0, 0);
                ahz[rt] = __builtin_amdgcn_mfma_f32_16x16x32_bf16(ah[rt][t], bhz, ahz[rt], 0, 0, 0);
                ahn[rt] = __builtin_amdgcn_mfma_f32_16x16x32_bf16(ah[rt][t], bhn, ahn[rt], 0, 0, 0);
            }
        }

        float b_ir = bih[col], b_iz = bih[128 + col], b_in = bih[256 + col];
        float b_hr = bhh[col], b_hz = bhh[128 + col], b_hn = bhh[256 + col];
        float w0 = 0.f, w1 = 0.f;
        if (LOGITS) { float2 wv = *(const float2*)(Wo + col * 2); w0 = wv.x; w1 = wv.y; }
        for (int rt = 0; rt < 2; ++rt) {
            for (int r = 0; r < 4; ++r) {
                int row = r0 + rt * 16 + lq * 4 + r;
                float irv = air[rt][r] + b_ir, hrv = ahr[rt][r] + b_hr;
                float izv = aiz[rt][r] + b_iz, hzv = ahz[rt][r] + b_hz;
                float inv = ain[rt][r] + b_in, hnv = ahn[rt][r] + b_hn;
                float rg = 1.f / (1.f + __expf(-(irv + hrv)));
                float zg = 1.f / (1.f + __expf(-(izv + hzv)));
                float xx = inv + rg * hnv;
                float ng = 2.f / (1.f + __expf(-2.f * xx)) - 1.f;   // tanh
                bool ok = (row < n);
                float hv = ok ? hidf[(size_t)row * H + col] : 0.f;
                float hout = (1.f - zg) * ng + zg * hv;
                if (LOGITS) {
                    s0[rt][r] += hout * w0;
                    s1[rt][r] += hout * w1;
                } else if (ok) {
                    out[(size_t)row * H + col] = (bf16_t)hout;
                }
            }
        }

        if (ct + 1 < 8) {
            stage_write((ct + 1) & 1);
            __syncthreads();
        }
    }

    if (LOGITS) {
        for (int m = 1; m < 16; m <<= 1) {
            for (int rt = 0; rt < 2; ++rt)
                for (int r = 0; r < 4; ++r) {
                    s0[rt][r] += __shfl_xor(s0[rt][r], m);
                    s1[rt][r] += __shfl_xor(s1[rt][r], m);
                }
        }
        if (lrow == 0) {
            float bo0 = bo[0], bo1 = bo[1];
            for (int rt = 0; rt < 2; ++rt)
                for (int r = 0; r < 4; ++r) {
                    int row = r0 + rt * 16 + lq * 4 + r;
                    if (row < n) {
                        float l0 = s0[rt][r] + bo0, l1 = s1[rt][r] + bo1;
                        float mx = fmaxf(l0, l1);
                        float lse = mx + __logf(__expf(l0 - mx) + __expf(l1 - mx));
                        logits[(size_t)row * 2]     = l0 - lse;
                        logits[(size_t)row * 2 + 1] = l1 - lse;
                    }
                }
        }
    }
}

extern "C" void kernel_launch(void* const* d_in, const int* in_sizes, int n_in,
                              void* d_out, int out_size, void* d_ws, size_t ws_size,
                              hipStream_t stream) {
    const float* x   = (const float*)d_in[0];
    const int*   ei  = (const int*)d_in[1];
    const float* ew  = (const float*)d_in[2];
    const float* Wf  = (const float*)d_in[3];
    const float* bf  = (const float*)d_in[4];
    const float* Wih = (const float*)d_in[5];
    const float* bih = (const float*)d_in[6];
    const float* Whh = (const float*)d_in[7];
    const float* bhh = (const float*)d_in[8];
    const float* Wl1 = (const float*)d_in[9];
    const float* bl1 = (const float*)d_in[10];
    const float* Wo  = (const float*)d_in[11];
    const float* bo  = (const float*)d_in[12];

    int n  = in_sizes[0] / H;     // 100000
    int nE = in_sizes[2];         // 1600000

    float* hbuf   = (float*)d_ws;                         // [n][H] f32 hidden (GRU blend)
    bf16_t* hbufb = (bf16_t*)(hbuf + (size_t)n * H);      // [n][H] bf16 hidden
    bf16_t* b1b   = hbufb + (size_t)n * H;                // [n][H] bf16
    bf16_t* b2b   = b1b + (size_t)n * H;                  // [n][H] bf16
    bf16_t* wfT   = b2b + (size_t)n * H;
    bf16_t* wih   = wfT + 128 * 128;
    bf16_t* whh   = wih + 384 * 128;
    bf16_t* wl1T  = whh + 384 * 128;
    int* deg    = (int*)(wl1T + 128 * 128);               // [n]
    int* rowptr = deg + n;                                // [n+1]
    int* cursor = rowptr + (n + 1);                       // [n]
    int2* srcw  = (int2*)((char*)(cursor + n) + ((size_t)(-(intptr_t)(cursor + n)) & 7)); // [nE]

    int gemmGrid = (n + 127) / 128;
    int nScanBlocks = (n + SCAN_CHUNK - 1) / SCAN_CHUNK;

    // ---- weights + CSR build ----
    prep_weights<<<192, 256, 0, stream>>>(Wf, Wih, Whh, Wl1, wfT, wih, whh, wl1T);
    hipMemsetAsync(deg, 0, (size_t)n * sizeof(int), stream);
    hist_kernel<<<(nE + 255) / 256, 256, 0, stream>>>(ei, deg, nE);
    scan1_kernel<<<nScanBlocks, SCAN_T, 0, stream>>>(deg, rowptr, cursor, n);
    scan2_kernel<<<1, SCAN_T, 0, stream>>>(cursor, nScanBlocks);
    scan3_kernel<<<(n + 255) / 256, 256, 0, stream>>>(rowptr, deg, cursor, n, nE);
    scatter_kernel<<<(nE + 255) / 256, 256, 0, stream>>>(ei, ew, deg, srcw, nE);

    // ---- pipeline ----
    lin_first_kernel<<<gemmGrid, 256, 0, stream>>>(x, wfT, bf, hbuf, hbufb, n);
    conv_csr_kernel<<<(n + 3) / 4, 256, 0, stream>>>(hbufb, rowptr, srcw, b1b, n);
    gru_kernel<false><<<gemmGrid, 256, 0, stream>>>(b1b, hbufb, hbuf, wih, whh, bih, bhh,
                                                    b1b, nullptr, nullptr, nullptr, n);
    lin_mid_kernel<<<gemmGrid, 256, 0, stream>>>(b1b, wl1T, bl1, b2b, n);
    conv_csr_kernel<<<(n + 3) / 4, 256, 0, stream>>>(b2b, rowptr, srcw, b1b, n);
    gru_kernel<true><<<gemmGrid, 256, 0, stream>>>(b1b, hbufb, hbuf, wih, whh, bih, bhh,
                                                   nullptr, Wo, bo, (float*)d_out, n);
}